// Round 5
// baseline (689.526 us; speedup 1.0000x reference)
//
#include <hip/hip_runtime.h>
#include <hip/hip_bf16.h>

#define NN 50000
#define NE 500000
#define DD 128
#define HCC 128
#define TDD 32
#define MDD 64

typedef __hip_bfloat16 bf16;
typedef _Float16 f16;
typedef __attribute__((ext_vector_type(8))) _Float16 f16x8;
typedef __attribute__((ext_vector_type(2))) _Float16 f16x2;
typedef __attribute__((ext_vector_type(4))) float f32x4;

__device__ __forceinline__ float2 bf2x(unsigned u) {
    union { unsigned v; float f; } a, b;
    a.v = u << 16; b.v = u & 0xffff0000u;
    float2 r; r.x = a.f; r.y = b.f; return r;
}

#if defined(__has_builtin) && __has_builtin(__builtin_amdgcn_fdot2)
#define FDOT2(a, b, acc) __builtin_amdgcn_fdot2((a), (b), (acc), false)
#else
__device__ __forceinline__ float fdot2_sw(f16x2 a, f16x2 b, float acc) {
    acc = fmaf((float)a[0], (float)b[0], acc);
    return fmaf((float)a[1], (float)b[1], acc);
}
#define FDOT2(a, b, acc) fdot2_sw((a), (b), (acc))
#endif

// VALU-speed 16-lane row reduction: v_add_f32_dpp row_ror:N.
// After ror 1,2,4,8 every lane in a 16-lane row holds the row sum.
template <int CTRL>
__device__ __forceinline__ float rot_add(float x) {
    int r = __builtin_amdgcn_update_dpp(0, __float_as_int(x), CTRL, 0xF, 0xF, true);
    return x + __int_as_float(r);
}
__device__ __forceinline__ float row_reduce16(float x) {
    x = rot_add<0x121>(x);  // row_ror:1
    x = rot_add<0x122>(x);  // row_ror:2
    x = rot_add<0x124>(x);  // row_ror:4
    x = rot_add<0x128>(x);  // row_ror:8
    return x;
}

// ---------------------------------------------------------------------------
// conv_w: WTh[n][k] = Wcat[k][n] (f16, n in [0,512): q|k|v|skip), Weh = We f16,
// and zero cnt[NN+1] (last element doubles as agg's work counter).
// ---------------------------------------------------------------------------
__global__ __launch_bounds__(256) void conv_w_kernel(
    const float* __restrict__ Wq, const float* __restrict__ Wk,
    const float* __restrict__ Wv, const float* __restrict__ Wsk,
    const float* __restrict__ We,
    f16* __restrict__ WTh, f16* __restrict__ Weh, int* __restrict__ cnt)
{
    int idx = blockIdx.x * 256 + threadIdx.x;
    if (idx < 512 * 128) {
        int n = idx >> 7, k = idx & 127;
        int mat = n >> 7, col = n & 127;
        const float* W = (mat == 0) ? Wq : (mat == 1) ? Wk : (mat == 2) ? Wv : Wsk;
        WTh[idx] = (f16)W[k * 128 + col];
    } else if (idx < 512 * 128 + 96 * 128) {
        int i = idx - 512 * 128;
        Weh[i] = (f16)We[i];
    } else if (idx < 512 * 128 + 96 * 128 + NN + 1) {
        cnt[idx - (512 * 128 + 96 * 128)] = 0;
    }
}

// ---------------------------------------------------------------------------
// K1 (MFMA): out[g] = x @ W[g] + b[g].  grid = (782, 4).
// g==0 -> qh; g==1/2 -> interleaved kvh row (blocks of 8: k[4j..4j+3] v[4j..4j+3],
// so agg reads one 16B f16x8 per lane covering its 4 k-dims AND 4 v-dims);
// g==3 -> f32 skip written to outp.
// ---------------------------------------------------------------------------
__global__ __launch_bounds__(256) void node_proj_kernel(
    const float* __restrict__ x, const f16* __restrict__ WTh,
    const float* __restrict__ bq, const float* __restrict__ bk,
    const float* __restrict__ bv, const float* __restrict__ bsk,
    f16* __restrict__ qh, f16* __restrict__ kvh,
    float* __restrict__ outp)
{
    __shared__ f16 xs[64 * 136];    // 17408 B
    __shared__ f16 ws[128 * 136];   // 34816 B

    const int node0 = blockIdx.x * 64;
    const int g = blockIdx.y;

    // stage x tile (64 x 128), f32 -> f16 on the fly
    for (int i = threadIdx.x; i < 64 * 32; i += 256) {
        int node = i >> 5, koff = (i & 31) * 4;
        int gn = node0 + node;
        f16 o4[4] = { (f16)0.f, (f16)0.f, (f16)0.f, (f16)0.f };
        if (gn < NN) {
            float4 v = *(const float4*)&x[(size_t)gn * DD + koff];
            o4[0] = (f16)v.x; o4[1] = (f16)v.y; o4[2] = (f16)v.z; o4[3] = (f16)v.w;
        }
        *(uint2*)&xs[node * 136 + koff] = *(uint2*)o4;
    }
    // stage W^T tile (128 cols x 128 k) for matrix g
    const f16* wt = WTh + (size_t)g * 128 * 128;
    for (int i = threadIdx.x; i < 128 * 32; i += 256) {
        int n = i >> 5, koff = (i & 31) * 4;
        *(uint2*)&ws[n * 136 + koff] = *(const uint2*)&wt[n * 128 + koff];
    }
    __syncthreads();

    const int wave = threadIdx.x >> 6;
    const int lane = threadIdx.x & 63;
    const int m0 = wave * 16;
    const int lrow = lane & 15;          // A/B row-or-col index
    const int lk = (lane >> 4) * 8;      // k-chunk offset within 32

    f32x4 acc[8];
    #pragma unroll
    for (int t = 0; t < 8; t++) acc[t] = (f32x4){0.f, 0.f, 0.f, 0.f};

    #pragma unroll
    for (int kc = 0; kc < 4; kc++) {
        f16x8 a = *(const f16x8*)&xs[(m0 + lrow) * 136 + kc * 32 + lk];
        #pragma unroll
        for (int t = 0; t < 8; t++) {
            f16x8 b = *(const f16x8*)&ws[(t * 16 + lrow) * 136 + kc * 32 + lk];
            acc[t] = __builtin_amdgcn_mfma_f32_16x16x32_f16(a, b, acc[t], 0, 0, 0);
        }
    }

    const float* bias = (g == 0) ? bq : (g == 1) ? bk : (g == 2) ? bv : bsk;

    #pragma unroll 1
    for (int t = 0; t < 8; t++) {
        int col = t * 16 + lrow;
        float bc = bias[col];
        #pragma unroll
        for (int r = 0; r < 4; r++) {
            int node = node0 + m0 + (lane >> 4) * 4 + r;
            if (node < NN) {
                float val = acc[t][r] + bc;
                if (g == 0)      qh[(size_t)node * DD + col] = (f16)val;
                else if (g == 3) outp[(size_t)node * HCC + col] = val;
                else {
                    int off = 8 * (col >> 2) + (col & 3) + ((g == 2) ? 4 : 0);
                    kvh[(size_t)node * 256 + off] = (f16)val;
                }
            }
        }
    }
}

// ---------------------------------------------------------------------------
// K1b (MFMA): G[n][h*96+j] = sum_c qh[n][h*64+c] * Weh[j][h*64+c]  (bf16 out)
// Block: 64 nodes x 192 cols; wave: 16 nodes, 12 col-tiles (h = t/6), K=64.
// ---------------------------------------------------------------------------
__global__ __launch_bounds__(256) void g_kernel(
    const f16* __restrict__ qh, const f16* __restrict__ Weh,
    bf16* __restrict__ G)
{
    __shared__ f16 qs[64 * 136];   // 17408 B
    __shared__ f16 ws[96 * 136];   // 26112 B

    const int node0 = blockIdx.x * 64;
    for (int i = threadIdx.x; i < 64 * 32; i += 256) {
        int node = i >> 5, koff = (i & 31) * 4;
        int gn = node0 + node;
        uint2 val = {0u, 0u};
        if (gn < NN) val = *(const uint2*)&qh[(size_t)gn * DD + koff];
        *(uint2*)&qs[node * 136 + koff] = val;
    }
    for (int i = threadIdx.x; i < 96 * 32; i += 256) {
        int j = i >> 5, koff = (i & 31) * 4;
        *(uint2*)&ws[j * 136 + koff] = *(const uint2*)&Weh[j * 128 + koff];
    }
    __syncthreads();

    const int wave = threadIdx.x >> 6;
    const int lane = threadIdx.x & 63;
    const int m0 = wave * 16;
    const int lrow = lane & 15;
    const int lk = (lane >> 4) * 8;

    // preload the 4 A-fragments: (h, kc) in {0,1} x {0,1}
    f16x8 afr[4];
    #pragma unroll
    for (int hk = 0; hk < 4; hk++) {
        int h = hk >> 1, kc = hk & 1;
        afr[hk] = *(const f16x8*)&qs[(m0 + lrow) * 136 + h * 64 + kc * 32 + lk];
    }

    f32x4 acc[12];
    #pragma unroll
    for (int t = 0; t < 12; t++) acc[t] = (f32x4){0.f, 0.f, 0.f, 0.f};

    #pragma unroll
    for (int t = 0; t < 12; t++) {
        int h = (t < 6) ? 0 : 1;
        int jt = (t < 6) ? t : t - 6;
        #pragma unroll
        for (int kc = 0; kc < 2; kc++) {
            f16x8 b = *(const f16x8*)&ws[(jt * 16 + lrow) * 136 + h * 64 + kc * 32 + lk];
            acc[t] = __builtin_amdgcn_mfma_f32_16x16x32_f16(afr[h * 2 + kc], b, acc[t], 0, 0, 0);
        }
    }

    #pragma unroll 1
    for (int t = 0; t < 12; t++) {
        int h = (t < 6) ? 0 : 1;
        int jt = (t < 6) ? t : t - 6;
        int col = h * 96 + jt * 16 + lrow;
        #pragma unroll
        for (int r = 0; r < 4; r++) {
            int node = node0 + m0 + (lane >> 4) * 4 + r;
            if (node < NN) G[(size_t)node * 192 + col] = __float2bfloat16(acc[t][r]);
        }
    }
}

// --------------------------- sort pipeline ----------------------------------
__global__ __launch_bounds__(256) void hist_kernel(
    const int* __restrict__ ei, int* __restrict__ cnt)
{
    int gid = blockIdx.x * 256 + threadIdx.x;
    if (gid < NE) atomicAdd(&cnt[ei[NE + gid]], 1);
}

__global__ __launch_bounds__(256) void scan_a_kernel(
    const int* __restrict__ cnt, int* __restrict__ bsum)
{
    __shared__ int red[256];
    int gid = blockIdx.x * 256 + threadIdx.x;
    red[threadIdx.x] = (gid < NN) ? cnt[gid] : 0;
    __syncthreads();
    for (int off = 128; off > 0; off >>= 1) {
        if (threadIdx.x < off) red[threadIdx.x] += red[threadIdx.x + off];
        __syncthreads();
    }
    if (threadIdx.x == 0) bsum[blockIdx.x] = red[0];
}

__global__ __launch_bounds__(256) void scan_b_kernel(
    const int* __restrict__ bsum, int* __restrict__ boff, int* __restrict__ seg)
{
    __shared__ int s[256];
    int t = threadIdx.x;
    s[t] = (t < 196) ? bsum[t] : 0;
    __syncthreads();
    if (t == 0) {
        int run = 0;
        for (int b = 0; b < 196; b++) { int v = s[b]; s[b] = run; run += v; }
        seg[NN] = NE;
    }
    __syncthreads();
    if (t < 196) boff[t] = s[t];
}

__global__ __launch_bounds__(256) void scan_c_kernel(
    const int* __restrict__ cnt, const int* __restrict__ boff,
    int* __restrict__ seg, int* __restrict__ cur)
{
    __shared__ int s[256];
    int gid = blockIdx.x * 256 + threadIdx.x;
    int v = (gid < NN) ? cnt[gid] : 0;
    s[threadIdx.x] = v;
    __syncthreads();
    for (int off = 1; off < 256; off <<= 1) {
        int t = (threadIdx.x >= off) ? s[threadIdx.x - off] : 0;
        __syncthreads();
        s[threadIdx.x] += t;
        __syncthreads();
    }
    int excl = s[threadIdx.x] - v + boff[blockIdx.x];
    if (gid < NN) { seg[gid] = excl; cur[gid] = excl; }
}

// scatter: one packed 16-B store per edge {src, perm, time_bits, dst}
__global__ __launch_bounds__(256) void scatter_kernel(
    const int* __restrict__ ei, const int* __restrict__ et,
    int* __restrict__ cur, int4* __restrict__ epack)
{
    int gid = blockIdx.x * 256 + threadIdx.x;
    if (gid < NE) {
        int d = ei[NE + gid];
        int pos = atomicAdd(&cur[d], 1);
        int4 p;
        p.x = ei[gid];
        p.y = gid;
        p.z = __float_as_int((float)et[gid]);
        p.w = d;
        epack[pos] = p;
    }
}

// ---------------------------------------------------------------------------
// mega-agg v3: wave per dst node, half-wave per edge, with
//  (a) dynamic node chunks from a global counter (fixes residency
//      quantization + degree stragglers; grid = residency = 2048 blocks),
//  (b) explicitly staged loads: e[4] -> kv[4]/m[4] -> compute (all 12 vmem
//      ops in flight before dependent compute),
//  (c) DPP row_ror reduction (VALU-speed) instead of 4 ds_swizzle shfls,
//      interleaved across the 4 pairs.
// ---------------------------------------------------------------------------
__global__ __launch_bounds__(256) void agg_kernel(
    const int4* __restrict__ epack, const float* __restrict__ msg,
    const float* __restrict__ Wt, const float* __restrict__ bt,
    const f16* __restrict__ qh, const f16* __restrict__ kvh,
    const bf16* __restrict__ G, const int* __restrict__ seg,
    int* __restrict__ wctr,
    float* __restrict__ Sv, float* __restrict__ dnv,
    float* __restrict__ outp)
{
    const int lane = threadIdx.x & 63;
    const int l31 = lane & 31;
    const int hl = (lane >> 4) & 1;   // head of this lane's 16-group
    const int c = lane & 15;
    const int halfid = lane >> 5;

    const float wt0 = Wt[2 * c], wt1 = Wt[2 * c + 1];
    const float bt0 = bt[2 * c], bt1 = bt[2 * c + 1];

    union QU { uint2 u; f16x2 h[2]; };
    union KVU { uint4 u4; f16x2 h[4]; };

    for (;;) {
        int n0;
        if (lane == 0) n0 = atomicAdd(wctr, 4);
        n0 = __shfl(n0, 0);
        if (n0 >= NN) break;
        const int nend = (n0 + 4 < NN) ? n0 + 4 : NN;

        for (int n = n0; n < nend; n++) {
            const int s0 = seg[n], s1 = seg[n + 1];

            QU q; q.u = *(const uint2*)&qh[(size_t)n * DD + 4 * l31];
            const bf16* grow = G + (size_t)n * 192 + 96 * hl;
            const float Gc0 = __bfloat162float(grow[2 * c]);
            const float Gc1 = __bfloat162float(grow[2 * c + 1]);
            const float Gm0 = __bfloat162float(grow[32 + 4 * c]);
            const float Gm1 = __bfloat162float(grow[33 + 4 * c]);
            const float Gm2 = __bfloat162float(grow[34 + 4 * c]);
            const float Gm3 = __bfloat162float(grow[35 + 4 * c]);

            f32x4 av = (f32x4){0.f, 0.f, 0.f, 0.f};
            f32x4 sm = (f32x4){0.f, 0.f, 0.f, 0.f};
            float accd = 0.f, sc0 = 0.f, sc1 = 0.f;

            int ib = s0;
            #pragma unroll 1
            for (; ib + 8 <= s1; ib += 8) {
                // stage 1: 4 epack loads
                int4 e[4];
                #pragma unroll
                for (int u = 0; u < 4; u++) e[u] = epack[ib + 2 * u + halfid];
                // stage 2: 8 gathers (kv + msg), all independent
                KVU kv[4]; float4 m[4];
                #pragma unroll
                for (int u = 0; u < 4; u++) {
                    kv[u].u4 = *(const uint4*)&kvh[(size_t)e[u].x * 256 + 8 * l31];
                    m[u] = *(const float4*)&msg[((size_t)e[u].y << 6) + 4 * c];
                }
                // stage 3: per-edge partial scores
                float p[4], csa[4], csb[4];
                #pragma unroll
                for (int u = 0; u < 4; u++) {
                    float t = __int_as_float(e[u].z);
                    csa[u] = __cosf(fmaf(t, wt0, bt0));
                    csb[u] = __cosf(fmaf(t, wt1, bt1));
                    float pp = fmaf(csa[u], Gc0, csb[u] * Gc1);
                    pp = fmaf(m[u].x, Gm0, pp); pp = fmaf(m[u].y, Gm1, pp);
                    pp = fmaf(m[u].z, Gm2, pp); pp = fmaf(m[u].w, Gm3, pp);
                    pp = FDOT2(q.h[0], kv[u].h[0], pp);
                    pp = FDOT2(q.h[1], kv[u].h[1], pp);
                    p[u] = pp;
                }
                // stage 4: interleaved DPP row reductions
                #pragma unroll
                for (int u = 0; u < 4; u++) p[u] = rot_add<0x121>(p[u]);
                #pragma unroll
                for (int u = 0; u < 4; u++) p[u] = rot_add<0x122>(p[u]);
                #pragma unroll
                for (int u = 0; u < 4; u++) p[u] = rot_add<0x124>(p[u]);
                #pragma unroll
                for (int u = 0; u < 4; u++) p[u] = rot_add<0x128>(p[u]);
                // stage 5: exp + accumulate
                #pragma unroll
                for (int u = 0; u < 4; u++) {
                    float ex = __expf(p[u] * 0.125f);
                    av.x = fmaf(ex, (float)kv[u].h[2][0], av.x);
                    av.y = fmaf(ex, (float)kv[u].h[2][1], av.y);
                    av.z = fmaf(ex, (float)kv[u].h[3][0], av.z);
                    av.w = fmaf(ex, (float)kv[u].h[3][1], av.w);
                    accd += ex;
                    sc0 = fmaf(ex, csa[u], sc0);
                    sc1 = fmaf(ex, csb[u], sc1);
                    sm.x = fmaf(ex, m[u].x, sm.x);
                    sm.y = fmaf(ex, m[u].y, sm.y);
                    sm.z = fmaf(ex, m[u].z, sm.z);
                    sm.w = fmaf(ex, m[u].w, sm.w);
                }
            }
            #pragma unroll 1
            for (; ib < s1; ib += 2) {           // pair tail, odd-half predicated
                int iu = ib + halfid;
                bool pred = iu < s1;
                int4 e = epack[pred ? iu : s0];  // s0 valid: s0<s1 here
                KVU kv;
                kv.u4 = *(const uint4*)&kvh[(size_t)e.x * 256 + 8 * l31];
                float4 m = *(const float4*)&msg[((size_t)e.y << 6) + 4 * c];
                float t = __int_as_float(e.z);
                float cs0 = __cosf(fmaf(t, wt0, bt0));
                float cs1 = __cosf(fmaf(t, wt1, bt1));
                float pp = fmaf(cs0, Gc0, cs1 * Gc1);
                pp = fmaf(m.x, Gm0, pp); pp = fmaf(m.y, Gm1, pp);
                pp = fmaf(m.z, Gm2, pp); pp = fmaf(m.w, Gm3, pp);
                pp = FDOT2(q.h[0], kv.h[0], pp);
                pp = FDOT2(q.h[1], kv.h[1], pp);
                pp = row_reduce16(pp);
                float ex = pred ? __expf(pp * 0.125f) : 0.f;
                av.x = fmaf(ex, (float)kv.h[2][0], av.x);
                av.y = fmaf(ex, (float)kv.h[2][1], av.y);
                av.z = fmaf(ex, (float)kv.h[3][0], av.z);
                av.w = fmaf(ex, (float)kv.h[3][1], av.w);
                accd += ex;
                sc0 = fmaf(ex, cs0, sc0);
                sc1 = fmaf(ex, cs1, sc1);
                sm.x = fmaf(ex, m.x, sm.x);
                sm.y = fmaf(ex, m.y, sm.y);
                sm.z = fmaf(ex, m.z, sm.z);
                sm.w = fmaf(ex, m.w, sm.w);
            }

            // cross-half combine (halves held alternate edges of the same node)
            av.x += __shfl_xor(av.x, 32);
            av.y += __shfl_xor(av.y, 32);
            av.z += __shfl_xor(av.z, 32);
            av.w += __shfl_xor(av.w, 32);
            accd += __shfl_xor(accd, 32);
            sc0  += __shfl_xor(sc0, 32);
            sc1  += __shfl_xor(sc1, 32);
            sm.x += __shfl_xor(sm.x, 32);
            sm.y += __shfl_xor(sm.y, 32);
            sm.z += __shfl_xor(sm.z, 32);
            sm.w += __shfl_xor(sm.w, 32);

            if (lane < 32) {
                float dn = accd + 1e-16f;
                size_t sb = (size_t)n * 192 + 96 * hl;
                float2 scv; scv.x = sc0; scv.y = sc1;
                *(float2*)&Sv[sb + 2 * c] = scv;
                float4 smv; smv.x = sm.x; smv.y = sm.y; smv.z = sm.z; smv.w = sm.w;
                *(float4*)&Sv[sb + 32 + 4 * c] = smv;
                if (c == 0) dnv[2 * n + hl] = accd;   // lanes 0 and 16

                size_t nb = (size_t)n * HCC + 4 * l31;
                float4 sk = *(const float4*)&outp[nb];   // skip from node_proj
                float4 o;
                o.x = av.x / dn + sk.x;
                o.y = av.y / dn + sk.y;
                o.z = av.z / dn + sk.z;
                o.w = av.w / dn + sk.w;
                *(float4*)&outp[nb] = o;
            }
        }
    }
}

// ---------------------------------------------------------------------------
// K3: epilogue GEMM, out += (S @ We)/dn. 32 nodes/block, S transposed in LDS.
// ---------------------------------------------------------------------------
__global__ __launch_bounds__(256) void epi_kernel(
    const float* __restrict__ Sv, const float* __restrict__ dnv,
    const float* __restrict__ We, float* __restrict__ outp)
{
    __shared__ float st[192 * 36];  // 27.6 KB, st[c*36 + node]
    const int node0 = blockIdx.x * 32;
    for (int idx = threadIdx.x; idx < 32 * 192; idx += 256) {
        int n = idx / 192, c = idx - n * 192;
        int node = node0 + n;
        st[c * 36 + n] = (node < NN) ? Sv[(size_t)node * 192 + c] : 0.f;
    }
    __syncthreads();

    const int wave = threadIdx.x >> 6;
    const int lane = threadIdx.x & 63;
    const int nb = wave * 8;
    const int hoff = (lane < 32) ? 0 : 96;
    const float2* We2 = (const float2*)We;

    float a[8][2];
    #pragma unroll
    for (int n = 0; n < 8; n++) { a[n][0] = 0.f; a[n][1] = 0.f; }

    #pragma unroll 8
    for (int j = 0; j < 96; j++) {
        float2 w = We2[j * 64 + lane];
        const float* sr = &st[(hoff + j) * 36 + nb];
        float sv[8];
        *(float4*)&sv[0] = *(const float4*)sr;
        *(float4*)&sv[4] = *(const float4*)(sr + 4);
        #pragma unroll
        for (int n = 0; n < 8; n++) {
            a[n][0] = fmaf(sv[n], w.x, a[n][0]);
            a[n][1] = fmaf(sv[n], w.y, a[n][1]);
        }
    }

    #pragma unroll 1
    for (int n = 0; n < 8; n++) {
        int node = node0 + nb + n;
        if (node >= NN) break;
        float dn = dnv[node * 2 + (lane >> 5)] + 1e-16f;
        size_t b = (size_t)node * HCC + 2 * lane;
        float2 o = *(const float2*)&outp[b];
        o.x += a[n][0] / dn;
        o.y += a[n][1] / dn;
        *(float2*)&outp[b] = o;
    }
}

extern "C" void kernel_launch(void* const* d_in, const int* in_sizes, int n_in,
                              void* d_out, int out_size, void* d_ws, size_t ws_size,
                              hipStream_t stream) {
    const float* x   = (const float*)d_in[0];
    const int* ei    = (const int*)d_in[1];
    const int* et    = (const int*)d_in[2];
    const float* msg = (const float*)d_in[3];
    const float* Wt  = (const float*)d_in[4];
    const float* bt  = (const float*)d_in[5];
    const float* Wq  = (const float*)d_in[6];
    const float* bq  = (const float*)d_in[7];
    const float* Wk  = (const float*)d_in[8];
    const float* bk  = (const float*)d_in[9];
    const float* Wv  = (const float*)d_in[10];
    const float* bv  = (const float*)d_in[11];
    const float* We  = (const float*)d_in[12];
    const float* Wsk = (const float*)d_in[13];
    const float* bsk = (const float*)d_in[14];

    const size_t nf = (size_t)NN * HCC;
    f16* qh      = (f16*)d_ws;                    // NN*128
    f16* kvh     = qh + nf;                       // NN*256 (k/v interleaved)
    f16* WTh     = kvh + 2 * nf;                  // 512*128
    f16* Weh     = WTh + 512 * 128;               // 96*128
    bf16* G      = (bf16*)(Weh + 96 * 128);       // NN*192
    float* Sv    = (float*)(G + (size_t)NN * 192);// NN*192 f32
    float* dnv   = Sv + (size_t)NN * 192;         // NN*2
    int4* epack  = (int4*)(dnv + (size_t)NN * 2); // NE int4
    int* cnt     = (int*)(epack + NE);            // NN+1 (last = work counter)
    int* seg     = cnt + NN + 1;                  // NN+1
    int* cur     = seg + NN + 1;
    int* bsum    = cur + NN;
    int* boff    = bsum + 256;
    size_t need  = (size_t)((char*)(boff + 256) - (char*)d_ws);
    if (ws_size < need) return;

    int* wctr = cnt + NN;
    float* outp = (float*)d_out;

    conv_w_kernel<<<(512 * 128 + 96 * 128 + NN + 1 + 255) / 256, 256, 0, stream>>>(
        Wq, Wk, Wv, Wsk, We, WTh, Weh, cnt);
    dim3 npgrid((NN + 63) / 64, 4);
    node_proj_kernel<<<npgrid, 256, 0, stream>>>(
        x, WTh, bq, bk, bv, bsk, qh, kvh, outp);
    g_kernel<<<(NN + 63) / 64, 256, 0, stream>>>(qh, Weh, G);
    hist_kernel<<<(NE + 255) / 256, 256, 0, stream>>>(ei, cnt);
    scan_a_kernel<<<196, 256, 0, stream>>>(cnt, bsum);
    scan_b_kernel<<<1, 256, 0, stream>>>(bsum, boff, seg);
    scan_c_kernel<<<196, 256, 0, stream>>>(cnt, boff, seg, cur);
    scatter_kernel<<<(NE + 255) / 256, 256, 0, stream>>>(ei, et, cur, epack);
    agg_kernel<<<2048, 256, 0, stream>>>(
        epack, msg, Wt, bt, qh, kvh, G, seg, wctr, Sv, dnv, outp);
    epi_kernel<<<(NN + 31) / 32, 256, 0, stream>>>(Sv, dnv, We, outp);
}

// Round 6
// 530.261 us; speedup vs baseline: 1.3004x; 1.3004x over previous
//
#include <hip/hip_runtime.h>
#include <hip/hip_bf16.h>

#define NN 50000
#define NE 500000
#define DD 128
#define HCC 128
#define TDD 32
#define MDD 64

typedef __hip_bfloat16 bf16;
typedef _Float16 f16;
typedef __attribute__((ext_vector_type(8))) _Float16 f16x8;
typedef __attribute__((ext_vector_type(2))) _Float16 f16x2;
typedef __attribute__((ext_vector_type(4))) float f32x4;

__device__ __forceinline__ float2 bf2x(unsigned u) {
    union { unsigned v; float f; } a, b;
    a.v = u << 16; b.v = u & 0xffff0000u;
    float2 r; r.x = a.f; r.y = b.f; return r;
}

#if defined(__has_builtin) && __has_builtin(__builtin_amdgcn_fdot2)
#define FDOT2(a, b, acc) __builtin_amdgcn_fdot2((a), (b), (acc), false)
#else
__device__ __forceinline__ float fdot2_sw(f16x2 a, f16x2 b, float acc) {
    acc = fmaf((float)a[0], (float)b[0], acc);
    return fmaf((float)a[1], (float)b[1], acc);
}
#define FDOT2(a, b, acc) fdot2_sw((a), (b), (acc))
#endif

// VALU-speed 16-lane row reduction: v_add_f32_dpp row_ror:N.
// After ror 1,2,4,8 every lane in a 16-lane row holds the row sum.
template <int CTRL>
__device__ __forceinline__ float rot_add(float x) {
    int r = __builtin_amdgcn_update_dpp(0, __float_as_int(x), CTRL, 0xF, 0xF, true);
    return x + __int_as_float(r);
}
__device__ __forceinline__ float row_reduce16(float x) {
    x = rot_add<0x121>(x);  // row_ror:1
    x = rot_add<0x122>(x);  // row_ror:2
    x = rot_add<0x124>(x);  // row_ror:4
    x = rot_add<0x128>(x);  // row_ror:8
    return x;
}

// ---------------------------------------------------------------------------
// conv_w: WTh[n][k] = Wcat[k][n] (f16, n in [0,512): q|k|v|skip), Weh = We f16,
// and zero cnt.
// ---------------------------------------------------------------------------
__global__ __launch_bounds__(256) void conv_w_kernel(
    const float* __restrict__ Wq, const float* __restrict__ Wk,
    const float* __restrict__ Wv, const float* __restrict__ Wsk,
    const float* __restrict__ We,
    f16* __restrict__ WTh, f16* __restrict__ Weh, int* __restrict__ cnt)
{
    int idx = blockIdx.x * 256 + threadIdx.x;
    if (idx < 512 * 128) {
        int n = idx >> 7, k = idx & 127;
        int mat = n >> 7, col = n & 127;
        const float* W = (mat == 0) ? Wq : (mat == 1) ? Wk : (mat == 2) ? Wv : Wsk;
        WTh[idx] = (f16)W[k * 128 + col];
    } else if (idx < 512 * 128 + 96 * 128) {
        int i = idx - 512 * 128;
        Weh[i] = (f16)We[i];
    } else if (idx < 512 * 128 + 96 * 128 + NN) {
        cnt[idx - (512 * 128 + 96 * 128)] = 0;
    }
}

// ---------------------------------------------------------------------------
// K1 (MFMA): out[g] = x @ W[g] + b[g].  grid = (782, 4).
// g==0 -> qh; g==1/2 -> interleaved kvh row (blocks of 8: k[4j..4j+3] v[4j..4j+3],
// so agg reads one 16B f16x8 per lane covering its 4 k-dims AND 4 v-dims);
// g==3 -> f32 skip written to outp.
// ---------------------------------------------------------------------------
__global__ __launch_bounds__(256) void node_proj_kernel(
    const float* __restrict__ x, const f16* __restrict__ WTh,
    const float* __restrict__ bq, const float* __restrict__ bk,
    const float* __restrict__ bv, const float* __restrict__ bsk,
    f16* __restrict__ qh, f16* __restrict__ kvh,
    float* __restrict__ outp)
{
    __shared__ f16 xs[64 * 136];    // 17408 B
    __shared__ f16 ws[128 * 136];   // 34816 B

    const int node0 = blockIdx.x * 64;
    const int g = blockIdx.y;

    // stage x tile (64 x 128), f32 -> f16 on the fly
    for (int i = threadIdx.x; i < 64 * 32; i += 256) {
        int node = i >> 5, koff = (i & 31) * 4;
        int gn = node0 + node;
        f16 o4[4] = { (f16)0.f, (f16)0.f, (f16)0.f, (f16)0.f };
        if (gn < NN) {
            float4 v = *(const float4*)&x[(size_t)gn * DD + koff];
            o4[0] = (f16)v.x; o4[1] = (f16)v.y; o4[2] = (f16)v.z; o4[3] = (f16)v.w;
        }
        *(uint2*)&xs[node * 136 + koff] = *(uint2*)o4;
    }
    // stage W^T tile (128 cols x 128 k) for matrix g
    const f16* wt = WTh + (size_t)g * 128 * 128;
    for (int i = threadIdx.x; i < 128 * 32; i += 256) {
        int n = i >> 5, koff = (i & 31) * 4;
        *(uint2*)&ws[n * 136 + koff] = *(const uint2*)&wt[n * 128 + koff];
    }
    __syncthreads();

    const int wave = threadIdx.x >> 6;
    const int lane = threadIdx.x & 63;
    const int m0 = wave * 16;
    const int lrow = lane & 15;          // A/B row-or-col index
    const int lk = (lane >> 4) * 8;      // k-chunk offset within 32

    f32x4 acc[8];
    #pragma unroll
    for (int t = 0; t < 8; t++) acc[t] = (f32x4){0.f, 0.f, 0.f, 0.f};

    #pragma unroll
    for (int kc = 0; kc < 4; kc++) {
        f16x8 a = *(const f16x8*)&xs[(m0 + lrow) * 136 + kc * 32 + lk];
        #pragma unroll
        for (int t = 0; t < 8; t++) {
            f16x8 b = *(const f16x8*)&ws[(t * 16 + lrow) * 136 + kc * 32 + lk];
            acc[t] = __builtin_amdgcn_mfma_f32_16x16x32_f16(a, b, acc[t], 0, 0, 0);
        }
    }

    const float* bias = (g == 0) ? bq : (g == 1) ? bk : (g == 2) ? bv : bsk;

    #pragma unroll 1
    for (int t = 0; t < 8; t++) {
        int col = t * 16 + lrow;
        float bc = bias[col];
        #pragma unroll
        for (int r = 0; r < 4; r++) {
            int node = node0 + m0 + (lane >> 4) * 4 + r;
            if (node < NN) {
                float val = acc[t][r] + bc;
                if (g == 0)      qh[(size_t)node * DD + col] = (f16)val;
                else if (g == 3) outp[(size_t)node * HCC + col] = val;
                else {
                    int off = 8 * (col >> 2) + (col & 3) + ((g == 2) ? 4 : 0);
                    kvh[(size_t)node * 256 + off] = (f16)val;
                }
            }
        }
    }
}

// ---------------------------------------------------------------------------
// K1b (MFMA): G[n][h*96+j] = sum_c qh[n][h*64+c] * Weh[j][h*64+c]  (bf16 out)
// Block: 64 nodes x 192 cols; wave: 16 nodes, 12 col-tiles (h = t/6), K=64.
// ---------------------------------------------------------------------------
__global__ __launch_bounds__(256) void g_kernel(
    const f16* __restrict__ qh, const f16* __restrict__ Weh,
    bf16* __restrict__ G)
{
    __shared__ f16 qs[64 * 136];   // 17408 B
    __shared__ f16 ws[96 * 136];   // 26112 B

    const int node0 = blockIdx.x * 64;
    for (int i = threadIdx.x; i < 64 * 32; i += 256) {
        int node = i >> 5, koff = (i & 31) * 4;
        int gn = node0 + node;
        uint2 val = {0u, 0u};
        if (gn < NN) val = *(const uint2*)&qh[(size_t)gn * DD + koff];
        *(uint2*)&qs[node * 136 + koff] = val;
    }
    for (int i = threadIdx.x; i < 96 * 32; i += 256) {
        int j = i >> 5, koff = (i & 31) * 4;
        *(uint2*)&ws[j * 136 + koff] = *(const uint2*)&Weh[j * 128 + koff];
    }
    __syncthreads();

    const int wave = threadIdx.x >> 6;
    const int lane = threadIdx.x & 63;
    const int m0 = wave * 16;
    const int lrow = lane & 15;
    const int lk = (lane >> 4) * 8;

    // preload the 4 A-fragments: (h, kc) in {0,1} x {0,1}
    f16x8 afr[4];
    #pragma unroll
    for (int hk = 0; hk < 4; hk++) {
        int h = hk >> 1, kc = hk & 1;
        afr[hk] = *(const f16x8*)&qs[(m0 + lrow) * 136 + h * 64 + kc * 32 + lk];
    }

    f32x4 acc[12];
    #pragma unroll
    for (int t = 0; t < 12; t++) acc[t] = (f32x4){0.f, 0.f, 0.f, 0.f};

    #pragma unroll
    for (int t = 0; t < 12; t++) {
        int h = (t < 6) ? 0 : 1;
        int jt = (t < 6) ? t : t - 6;
        #pragma unroll
        for (int kc = 0; kc < 2; kc++) {
            f16x8 b = *(const f16x8*)&ws[(jt * 16 + lrow) * 136 + h * 64 + kc * 32 + lk];
            acc[t] = __builtin_amdgcn_mfma_f32_16x16x32_f16(afr[h * 2 + kc], b, acc[t], 0, 0, 0);
        }
    }

    #pragma unroll 1
    for (int t = 0; t < 12; t++) {
        int h = (t < 6) ? 0 : 1;
        int jt = (t < 6) ? t : t - 6;
        int col = h * 96 + jt * 16 + lrow;
        #pragma unroll
        for (int r = 0; r < 4; r++) {
            int node = node0 + m0 + (lane >> 4) * 4 + r;
            if (node < NN) G[(size_t)node * 192 + col] = __float2bfloat16(acc[t][r]);
        }
    }
}

// --------------------------- sort pipeline ----------------------------------
__global__ __launch_bounds__(256) void hist_kernel(
    const int* __restrict__ ei, int* __restrict__ cnt)
{
    int gid = blockIdx.x * 256 + threadIdx.x;
    if (gid < NE) atomicAdd(&cnt[ei[NE + gid]], 1);
}

__global__ __launch_bounds__(256) void scan_a_kernel(
    const int* __restrict__ cnt, int* __restrict__ bsum)
{
    __shared__ int red[256];
    int gid = blockIdx.x * 256 + threadIdx.x;
    red[threadIdx.x] = (gid < NN) ? cnt[gid] : 0;
    __syncthreads();
    for (int off = 128; off > 0; off >>= 1) {
        if (threadIdx.x < off) red[threadIdx.x] += red[threadIdx.x + off];
        __syncthreads();
    }
    if (threadIdx.x == 0) bsum[blockIdx.x] = red[0];
}

__global__ __launch_bounds__(256) void scan_b_kernel(
    const int* __restrict__ bsum, int* __restrict__ boff, int* __restrict__ seg)
{
    __shared__ int s[256];
    int t = threadIdx.x;
    s[t] = (t < 196) ? bsum[t] : 0;
    __syncthreads();
    if (t == 0) {
        int run = 0;
        for (int b = 0; b < 196; b++) { int v = s[b]; s[b] = run; run += v; }
        seg[NN] = NE;
    }
    __syncthreads();
    if (t < 196) boff[t] = s[t];
}

__global__ __launch_bounds__(256) void scan_c_kernel(
    const int* __restrict__ cnt, const int* __restrict__ boff,
    int* __restrict__ seg, int* __restrict__ cur)
{
    __shared__ int s[256];
    int gid = blockIdx.x * 256 + threadIdx.x;
    int v = (gid < NN) ? cnt[gid] : 0;
    s[threadIdx.x] = v;
    __syncthreads();
    for (int off = 1; off < 256; off <<= 1) {
        int t = (threadIdx.x >= off) ? s[threadIdx.x - off] : 0;
        __syncthreads();
        s[threadIdx.x] += t;
        __syncthreads();
    }
    int excl = s[threadIdx.x] - v + boff[blockIdx.x];
    if (gid < NN) { seg[gid] = excl; cur[gid] = excl; }
}

// scatter: one packed 16-B store per edge {src, perm, time_bits, dst}
__global__ __launch_bounds__(256) void scatter_kernel(
    const int* __restrict__ ei, const int* __restrict__ et,
    int* __restrict__ cur, int4* __restrict__ epack)
{
    int gid = blockIdx.x * 256 + threadIdx.x;
    if (gid < NE) {
        int d = ei[NE + gid];
        int pos = atomicAdd(&cur[d], 1);
        int4 p;
        p.x = ei[gid];
        p.y = gid;
        p.z = __float_as_int((float)et[gid]);
        p.w = d;
        epack[pos] = p;
    }
}

// ---------------------------------------------------------------------------
// mega-agg v4: wave per dst node, half-wave per edge.
// STATIC grid-stride node assignment (wave-uniform n -> scalarized seg loads
// and scalar loop branches; R4's dynamic atomic counter serialized the
// machine and is reverted). Grid = 2048 blocks = full residency, so every
// wave is resident from t=0 (fixes R3's two-round occupancy cliff).
// Staged loads: e[4] -> kv[4]/m[4] -> compute (12 vmem ops in flight).
// DPP row_ror reduction (VALU speed) instead of ds_swizzle shfls.
// ---------------------------------------------------------------------------
__global__ __launch_bounds__(256) void agg_kernel(
    const int4* __restrict__ epack, const float* __restrict__ msg,
    const float* __restrict__ Wt, const float* __restrict__ bt,
    const f16* __restrict__ qh, const f16* __restrict__ kvh,
    const bf16* __restrict__ G, const int* __restrict__ seg,
    float* __restrict__ Sv, float* __restrict__ dnv,
    float* __restrict__ outp)
{
    const int lane = threadIdx.x & 63;
    const int l31 = lane & 31;
    const int hl = (lane >> 4) & 1;   // head of this lane's 16-group
    const int c = lane & 15;
    const int halfid = lane >> 5;

    const float wt0 = Wt[2 * c], wt1 = Wt[2 * c + 1];
    const float bt0 = bt[2 * c], bt1 = bt[2 * c + 1];

    const int gw = blockIdx.x * 4 + (threadIdx.x >> 6);
    const int NW = gridDim.x * 4;

    union QU { uint2 u; f16x2 h[2]; };
    union KVU { uint4 u4; f16x2 h[4]; };

    for (int n = gw; n < NN; n += NW) {
        const int s0 = seg[n], s1 = seg[n + 1];

        QU q; q.u = *(const uint2*)&qh[(size_t)n * DD + 4 * l31];
        const bf16* grow = G + (size_t)n * 192 + 96 * hl;
        const float Gc0 = __bfloat162float(grow[2 * c]);
        const float Gc1 = __bfloat162float(grow[2 * c + 1]);
        const float Gm0 = __bfloat162float(grow[32 + 4 * c]);
        const float Gm1 = __bfloat162float(grow[33 + 4 * c]);
        const float Gm2 = __bfloat162float(grow[34 + 4 * c]);
        const float Gm3 = __bfloat162float(grow[35 + 4 * c]);

        f32x4 av = (f32x4){0.f, 0.f, 0.f, 0.f};
        f32x4 sm = (f32x4){0.f, 0.f, 0.f, 0.f};
        float accd = 0.f, sc0 = 0.f, sc1 = 0.f;

        int ib = s0;
        #pragma unroll 1
        for (; ib + 8 <= s1; ib += 8) {
            // stage 1: 4 epack loads
            int4 e[4];
            #pragma unroll
            for (int u = 0; u < 4; u++) e[u] = epack[ib + 2 * u + halfid];
            // stage 2: 8 gathers (kv + msg), all independent
            KVU kv[4]; float4 m[4];
            #pragma unroll
            for (int u = 0; u < 4; u++) {
                kv[u].u4 = *(const uint4*)&kvh[(size_t)e[u].x * 256 + 8 * l31];
                m[u] = *(const float4*)&msg[((size_t)e[u].y << 6) + 4 * c];
            }
            // stage 3: per-edge partial scores
            float p[4], csa[4], csb[4];
            #pragma unroll
            for (int u = 0; u < 4; u++) {
                float t = __int_as_float(e[u].z);
                csa[u] = __cosf(fmaf(t, wt0, bt0));
                csb[u] = __cosf(fmaf(t, wt1, bt1));
                float pp = fmaf(csa[u], Gc0, csb[u] * Gc1);
                pp = fmaf(m[u].x, Gm0, pp); pp = fmaf(m[u].y, Gm1, pp);
                pp = fmaf(m[u].z, Gm2, pp); pp = fmaf(m[u].w, Gm3, pp);
                pp = FDOT2(q.h[0], kv[u].h[0], pp);
                pp = FDOT2(q.h[1], kv[u].h[1], pp);
                p[u] = pp;
            }
            // stage 4: interleaved DPP row reductions
            #pragma unroll
            for (int u = 0; u < 4; u++) p[u] = rot_add<0x121>(p[u]);
            #pragma unroll
            for (int u = 0; u < 4; u++) p[u] = rot_add<0x122>(p[u]);
            #pragma unroll
            for (int u = 0; u < 4; u++) p[u] = rot_add<0x124>(p[u]);
            #pragma unroll
            for (int u = 0; u < 4; u++) p[u] = rot_add<0x128>(p[u]);
            // stage 5: exp + accumulate
            #pragma unroll
            for (int u = 0; u < 4; u++) {
                float ex = __expf(p[u] * 0.125f);
                av.x = fmaf(ex, (float)kv[u].h[2][0], av.x);
                av.y = fmaf(ex, (float)kv[u].h[2][1], av.y);
                av.z = fmaf(ex, (float)kv[u].h[3][0], av.z);
                av.w = fmaf(ex, (float)kv[u].h[3][1], av.w);
                accd += ex;
                sc0 = fmaf(ex, csa[u], sc0);
                sc1 = fmaf(ex, csb[u], sc1);
                sm.x = fmaf(ex, m[u].x, sm.x);
                sm.y = fmaf(ex, m[u].y, sm.y);
                sm.z = fmaf(ex, m[u].z, sm.z);
                sm.w = fmaf(ex, m[u].w, sm.w);
            }
        }
        #pragma unroll 1
        for (; ib < s1; ib += 2) {           // pair tail, odd-half predicated
            int iu = ib + halfid;
            bool pred = iu < s1;
            int4 e = epack[pred ? iu : s0];  // s0 valid: s0<s1 here
            KVU kv;
            kv.u4 = *(const uint4*)&kvh[(size_t)e.x * 256 + 8 * l31];
            float4 m = *(const float4*)&msg[((size_t)e.y << 6) + 4 * c];
            float t = __int_as_float(e.z);
            float cs0 = __cosf(fmaf(t, wt0, bt0));
            float cs1 = __cosf(fmaf(t, wt1, bt1));
            float pp = fmaf(cs0, Gc0, cs1 * Gc1);
            pp = fmaf(m.x, Gm0, pp); pp = fmaf(m.y, Gm1, pp);
            pp = fmaf(m.z, Gm2, pp); pp = fmaf(m.w, Gm3, pp);
            pp = FDOT2(q.h[0], kv.h[0], pp);
            pp = FDOT2(q.h[1], kv.h[1], pp);
            pp = row_reduce16(pp);
            float ex = pred ? __expf(pp * 0.125f) : 0.f;
            av.x = fmaf(ex, (float)kv.h[2][0], av.x);
            av.y = fmaf(ex, (float)kv.h[2][1], av.y);
            av.z = fmaf(ex, (float)kv.h[3][0], av.z);
            av.w = fmaf(ex, (float)kv.h[3][1], av.w);
            accd += ex;
            sc0 = fmaf(ex, cs0, sc0);
            sc1 = fmaf(ex, cs1, sc1);
            sm.x = fmaf(ex, m.x, sm.x);
            sm.y = fmaf(ex, m.y, sm.y);
            sm.z = fmaf(ex, m.z, sm.z);
            sm.w = fmaf(ex, m.w, sm.w);
        }

        // cross-half combine (halves held alternate edges of the same node)
        av.x += __shfl_xor(av.x, 32);
        av.y += __shfl_xor(av.y, 32);
        av.z += __shfl_xor(av.z, 32);
        av.w += __shfl_xor(av.w, 32);
        accd += __shfl_xor(accd, 32);
        sc0  += __shfl_xor(sc0, 32);
        sc1  += __shfl_xor(sc1, 32);
        sm.x += __shfl_xor(sm.x, 32);
        sm.y += __shfl_xor(sm.y, 32);
        sm.z += __shfl_xor(sm.z, 32);
        sm.w += __shfl_xor(sm.w, 32);

        if (lane < 32) {
            float dn = accd + 1e-16f;
            size_t sb = (size_t)n * 192 + 96 * hl;
            float2 scv; scv.x = sc0; scv.y = sc1;
            *(float2*)&Sv[sb + 2 * c] = scv;
            float4 smv; smv.x = sm.x; smv.y = sm.y; smv.z = sm.z; smv.w = sm.w;
            *(float4*)&Sv[sb + 32 + 4 * c] = smv;
            if (c == 0) dnv[2 * n + hl] = accd;   // lanes 0 and 16

            size_t nb = (size_t)n * HCC + 4 * l31;
            float4 sk = *(const float4*)&outp[nb];   // skip from node_proj
            float4 o;
            o.x = av.x / dn + sk.x;
            o.y = av.y / dn + sk.y;
            o.z = av.z / dn + sk.z;
            o.w = av.w / dn + sk.w;
            *(float4*)&outp[nb] = o;
        }
    }
}

// ---------------------------------------------------------------------------
// K3: epilogue GEMM, out += (S @ We)/dn. 32 nodes/block, S transposed in LDS.
// ---------------------------------------------------------------------------
__global__ __launch_bounds__(256) void epi_kernel(
    const float* __restrict__ Sv, const float* __restrict__ dnv,
    const float* __restrict__ We, float* __restrict__ outp)
{
    __shared__ float st[192 * 36];  // 27.6 KB, st[c*36 + node]
    const int node0 = blockIdx.x * 32;
    for (int idx = threadIdx.x; idx < 32 * 192; idx += 256) {
        int n = idx / 192, c = idx - n * 192;
        int node = node0 + n;
        st[c * 36 + n] = (node < NN) ? Sv[(size_t)node * 192 + c] : 0.f;
    }
    __syncthreads();

    const int wave = threadIdx.x >> 6;
    const int lane = threadIdx.x & 63;
    const int nb = wave * 8;
    const int hoff = (lane < 32) ? 0 : 96;
    const float2* We2 = (const float2*)We;

    float a[8][2];
    #pragma unroll
    for (int n = 0; n < 8; n++) { a[n][0] = 0.f; a[n][1] = 0.f; }

    #pragma unroll 8
    for (int j = 0; j < 96; j++) {
        float2 w = We2[j * 64 + lane];
        const float* sr = &st[(hoff + j) * 36 + nb];
        float sv[8];
        *(float4*)&sv[0] = *(const float4*)sr;
        *(float4*)&sv[4] = *(const float4*)(sr + 4);
        #pragma unroll
        for (int n = 0; n < 8; n++) {
            a[n][0] = fmaf(sv[n], w.x, a[n][0]);
            a[n][1] = fmaf(sv[n], w.y, a[n][1]);
        }
    }

    #pragma unroll 1
    for (int n = 0; n < 8; n++) {
        int node = node0 + nb + n;
        if (node >= NN) break;
        float dn = dnv[node * 2 + (lane >> 5)] + 1e-16f;
        size_t b = (size_t)node * HCC + 2 * lane;
        float2 o = *(const float2*)&outp[b];
        o.x += a[n][0] / dn;
        o.y += a[n][1] / dn;
        *(float2*)&outp[b] = o;
    }
}

extern "C" void kernel_launch(void* const* d_in, const int* in_sizes, int n_in,
                              void* d_out, int out_size, void* d_ws, size_t ws_size,
                              hipStream_t stream) {
    const float* x   = (const float*)d_in[0];
    const int* ei    = (const int*)d_in[1];
    const int* et    = (const int*)d_in[2];
    const float* msg = (const float*)d_in[3];
    const float* Wt  = (const float*)d_in[4];
    const float* bt  = (const float*)d_in[5];
    const float* Wq  = (const float*)d_in[6];
    const float* bq  = (const float*)d_in[7];
    const float* Wk  = (const float*)d_in[8];
    const float* bk  = (const float*)d_in[9];
    const float* Wv  = (const float*)d_in[10];
    const float* bv  = (const float*)d_in[11];
    const float* We  = (const float*)d_in[12];
    const float* Wsk = (const float*)d_in[13];
    const float* bsk = (const float*)d_in[14];

    const size_t nf = (size_t)NN * HCC;
    f16* qh      = (f16*)d_ws;                    // NN*128
    f16* kvh     = qh + nf;                       // NN*256 (k/v interleaved)
    f16* WTh     = kvh + 2 * nf;                  // 512*128
    f16* Weh     = WTh + 512 * 128;               // 96*128
    bf16* G      = (bf16*)(Weh + 96 * 128);       // NN*192
    float* Sv    = (float*)(G + (size_t)NN * 192);// NN*192 f32
    float* dnv   = Sv + (size_t)NN * 192;         // NN*2
    int4* epack  = (int4*)(dnv + (size_t)NN * 2); // NE int4
    int* cnt     = (int*)(epack + NE);
    int* seg     = cnt + NN;                      // NN+1
    int* cur     = seg + NN + 1;
    int* bsum    = cur + NN;
    int* boff    = bsum + 256;
    size_t need  = (size_t)((char*)(boff + 256) - (char*)d_ws);
    if (ws_size < need) return;

    float* outp = (float*)d_out;

    conv_w_kernel<<<(512 * 128 + 96 * 128 + NN + 255) / 256, 256, 0, stream>>>(
        Wq, Wk, Wv, Wsk, We, WTh, Weh, cnt);
    dim3 npgrid((NN + 63) / 64, 4);
    node_proj_kernel<<<npgrid, 256, 0, stream>>>(
        x, WTh, bq, bk, bv, bsk, qh, kvh, outp);
    g_kernel<<<(NN + 63) / 64, 256, 0, stream>>>(qh, Weh, G);
    hist_kernel<<<(NE + 255) / 256, 256, 0, stream>>>(ei, cnt);
    scan_a_kernel<<<196, 256, 0, stream>>>(cnt, bsum);
    scan_b_kernel<<<1, 256, 0, stream>>>(bsum, boff, seg);
    scan_c_kernel<<<196, 256, 0, stream>>>(cnt, boff, seg, cur);
    scatter_kernel<<<(NE + 255) / 256, 256, 0, stream>>>(ei, et, cur, epack);
    agg_kernel<<<2048, 256, 0, stream>>>(
        epack, msg, Wt, bt, qh, kvh, G, seg, Sv, dnv, outp);
    epi_kernel<<<(NN + 31) / 32, 256, 0, stream>>>(Sv, dnv, We, outp);
}

// Round 9
// 521.022 us; speedup vs baseline: 1.3234x; 1.0177x over previous
//
#include <hip/hip_runtime.h>
#include <hip/hip_bf16.h>

#define NN 50000
#define NE 500000
#define DD 128
#define HCC 128
#define TDD 32
#define MDD 64

typedef __hip_bfloat16 bf16;
typedef _Float16 f16;
typedef __attribute__((ext_vector_type(8))) _Float16 f16x8;
typedef __attribute__((ext_vector_type(2))) _Float16 f16x2;
typedef __attribute__((ext_vector_type(4))) float f32x4;

__device__ __forceinline__ float2 bf2x(unsigned u) {
    union { unsigned v; float f; } a, b;
    a.v = u << 16; b.v = u & 0xffff0000u;
    float2 r; r.x = a.f; r.y = b.f; return r;
}

#if defined(__has_builtin) && __has_builtin(__builtin_amdgcn_fdot2)
#define FDOT2(a, b, acc) __builtin_amdgcn_fdot2((a), (b), (acc), false)
#else
__device__ __forceinline__ float fdot2_sw(f16x2 a, f16x2 b, float acc) {
    acc = fmaf((float)a[0], (float)b[0], acc);
    return fmaf((float)a[1], (float)b[1], acc);
}
#define FDOT2(a, b, acc) fdot2_sw((a), (b), (acc))
#endif

// VALU-speed 16-lane row reduction: v_add_f32_dpp row_ror:N.
// After ror 1,2,4,8 every lane in a 16-lane row holds the row sum.
template <int CTRL>
__device__ __forceinline__ float rot_add(float x) {
    int r = __builtin_amdgcn_update_dpp(0, __float_as_int(x), CTRL, 0xF, 0xF, true);
    return x + __int_as_float(r);
}

// ---------------------------------------------------------------------------
// conv_w: WTh[n][k] = Wcat[k][n] (f16, n in [0,512): q|k|v|skip), Weh = We f16,
// and zero cnt.
// ---------------------------------------------------------------------------
__global__ __launch_bounds__(256) void conv_w_kernel(
    const float* __restrict__ Wq, const float* __restrict__ Wk,
    const float* __restrict__ Wv, const float* __restrict__ Wsk,
    const float* __restrict__ We,
    f16* __restrict__ WTh, f16* __restrict__ Weh, int* __restrict__ cnt)
{
    int idx = blockIdx.x * 256 + threadIdx.x;
    if (idx < 512 * 128) {
        int n = idx >> 7, k = idx & 127;
        int mat = n >> 7, col = n & 127;
        const float* W = (mat == 0) ? Wq : (mat == 1) ? Wk : (mat == 2) ? Wv : Wsk;
        WTh[idx] = (f16)W[k * 128 + col];
    } else if (idx < 512 * 128 + 96 * 128) {
        int i = idx - 512 * 128;
        Weh[i] = (f16)We[i];
    } else if (idx < 512 * 128 + 96 * 128 + NN) {
        cnt[idx - (512 * 128 + 96 * 128)] = 0;
    }
}

// ---------------------------------------------------------------------------
// K1 (MFMA): out[g] = x @ W[g] + b[g].  grid = (782, 4).
// g==0 -> qh; g==1/2 -> interleaved kvh row (blocks of 8: k[4j..4j+3] v[4j..4j+3],
// so agg reads one 16B f16x8 per lane covering its 4 k-dims AND 4 v-dims);
// g==3 -> f32 skip written to outp.
// ---------------------------------------------------------------------------
__global__ __launch_bounds__(256) void node_proj_kernel(
    const float* __restrict__ x, const f16* __restrict__ WTh,
    const float* __restrict__ bq, const float* __restrict__ bk,
    const float* __restrict__ bv, const float* __restrict__ bsk,
    f16* __restrict__ qh, f16* __restrict__ kvh,
    float* __restrict__ outp)
{
    __shared__ f16 xs[64 * 136];    // 17408 B
    __shared__ f16 ws[128 * 136];   // 34816 B

    const int node0 = blockIdx.x * 64;
    const int g = blockIdx.y;

    // stage x tile (64 x 128), f32 -> f16 on the fly
    for (int i = threadIdx.x; i < 64 * 32; i += 256) {
        int node = i >> 5, koff = (i & 31) * 4;
        int gn = node0 + node;
        f16 o4[4] = { (f16)0.f, (f16)0.f, (f16)0.f, (f16)0.f };
        if (gn < NN) {
            float4 v = *(const float4*)&x[(size_t)gn * DD + koff];
            o4[0] = (f16)v.x; o4[1] = (f16)v.y; o4[2] = (f16)v.z; o4[3] = (f16)v.w;
        }
        *(uint2*)&xs[node * 136 + koff] = *(uint2*)o4;
    }
    // stage W^T tile (128 cols x 128 k) for matrix g
    const f16* wt = WTh + (size_t)g * 128 * 128;
    for (int i = threadIdx.x; i < 128 * 32; i += 256) {
        int n = i >> 5, koff = (i & 31) * 4;
        *(uint2*)&ws[n * 136 + koff] = *(const uint2*)&wt[n * 128 + koff];
    }
    __syncthreads();

    const int wave = threadIdx.x >> 6;
    const int lane = threadIdx.x & 63;
    const int m0 = wave * 16;
    const int lrow = lane & 15;          // A/B row-or-col index
    const int lk = (lane >> 4) * 8;      // k-chunk offset within 32

    f32x4 acc[8];
    #pragma unroll
    for (int t = 0; t < 8; t++) acc[t] = (f32x4){0.f, 0.f, 0.f, 0.f};

    #pragma unroll
    for (int kc = 0; kc < 4; kc++) {
        f16x8 a = *(const f16x8*)&xs[(m0 + lrow) * 136 + kc * 32 + lk];
        #pragma unroll
        for (int t = 0; t < 8; t++) {
            f16x8 b = *(const f16x8*)&ws[(t * 16 + lrow) * 136 + kc * 32 + lk];
            acc[t] = __builtin_amdgcn_mfma_f32_16x16x32_f16(a, b, acc[t], 0, 0, 0);
        }
    }

    const float* bias = (g == 0) ? bq : (g == 1) ? bk : (g == 2) ? bv : bsk;

    #pragma unroll 1
    for (int t = 0; t < 8; t++) {
        int col = t * 16 + lrow;
        float bc = bias[col];
        #pragma unroll
        for (int r = 0; r < 4; r++) {
            int node = node0 + m0 + (lane >> 4) * 4 + r;
            if (node < NN) {
                float val = acc[t][r] + bc;
                if (g == 0)      qh[(size_t)node * DD + col] = (f16)val;
                else if (g == 3) outp[(size_t)node * HCC + col] = val;
                else {
                    int off = 8 * (col >> 2) + (col & 3) + ((g == 2) ? 4 : 0);
                    kvh[(size_t)node * 256 + off] = (f16)val;
                }
            }
        }
    }
}

// ---------------------------------------------------------------------------
// K1b (MFMA): G[n][h*96+j] = sum_c qh[n][h*64+c] * Weh[j][h*64+c]  (bf16 out)
// Block: 64 nodes x 192 cols; wave: 16 nodes, 12 col-tiles (h = t/6), K=64.
// ---------------------------------------------------------------------------
__global__ __launch_bounds__(256) void g_kernel(
    const f16* __restrict__ qh, const f16* __restrict__ Weh,
    bf16* __restrict__ G)
{
    __shared__ f16 qs[64 * 136];   // 17408 B
    __shared__ f16 ws[96 * 136];   // 26112 B

    const int node0 = blockIdx.x * 64;
    for (int i = threadIdx.x; i < 64 * 32; i += 256) {
        int node = i >> 5, koff = (i & 31) * 4;
        int gn = node0 + node;
        uint2 val = {0u, 0u};
        if (gn < NN) val = *(const uint2*)&qh[(size_t)gn * DD + koff];
        *(uint2*)&qs[node * 136 + koff] = val;
    }
    for (int i = threadIdx.x; i < 96 * 32; i += 256) {
        int j = i >> 5, koff = (i & 31) * 4;
        *(uint2*)&ws[j * 136 + koff] = *(const uint2*)&Weh[j * 128 + koff];
    }
    __syncthreads();

    const int wave = threadIdx.x >> 6;
    const int lane = threadIdx.x & 63;
    const int m0 = wave * 16;
    const int lrow = lane & 15;
    const int lk = (lane >> 4) * 8;

    // preload the 4 A-fragments: (h, kc) in {0,1} x {0,1}
    f16x8 afr[4];
    #pragma unroll
    for (int hk = 0; hk < 4; hk++) {
        int h = hk >> 1, kc = hk & 1;
        afr[hk] = *(const f16x8*)&qs[(m0 + lrow) * 136 + h * 64 + kc * 32 + lk];
    }

    f32x4 acc[12];
    #pragma unroll
    for (int t = 0; t < 12; t++) acc[t] = (f32x4){0.f, 0.f, 0.f, 0.f};

    #pragma unroll
    for (int t = 0; t < 12; t++) {
        int h = (t < 6) ? 0 : 1;
        int jt = (t < 6) ? t : t - 6;
        #pragma unroll
        for (int kc = 0; kc < 2; kc++) {
            f16x8 b = *(const f16x8*)&ws[(jt * 16 + lrow) * 136 + h * 64 + kc * 32 + lk];
            acc[t] = __builtin_amdgcn_mfma_f32_16x16x32_f16(afr[h * 2 + kc], b, acc[t], 0, 0, 0);
        }
    }

    #pragma unroll 1
    for (int t = 0; t < 12; t++) {
        int h = (t < 6) ? 0 : 1;
        int jt = (t < 6) ? t : t - 6;
        int col = h * 96 + jt * 16 + lrow;
        #pragma unroll
        for (int r = 0; r < 4; r++) {
            int node = node0 + m0 + (lane >> 4) * 4 + r;
            if (node < NN) G[(size_t)node * 192 + col] = __float2bfloat16(acc[t][r]);
        }
    }
}

// --------------------------- sort pipeline ----------------------------------
__global__ __launch_bounds__(256) void hist_kernel(
    const int* __restrict__ ei, int* __restrict__ cnt)
{
    int gid = blockIdx.x * 256 + threadIdx.x;
    if (gid < NE) atomicAdd(&cnt[ei[NE + gid]], 1);
}

__global__ __launch_bounds__(256) void scan_a_kernel(
    const int* __restrict__ cnt, int* __restrict__ bsum)
{
    __shared__ int red[256];
    int gid = blockIdx.x * 256 + threadIdx.x;
    red[threadIdx.x] = (gid < NN) ? cnt[gid] : 0;
    __syncthreads();
    for (int off = 128; off > 0; off >>= 1) {
        if (threadIdx.x < off) red[threadIdx.x] += red[threadIdx.x + off];
        __syncthreads();
    }
    if (threadIdx.x == 0) bsum[blockIdx.x] = red[0];
}

__global__ __launch_bounds__(256) void scan_b_kernel(
    const int* __restrict__ bsum, int* __restrict__ boff, int* __restrict__ seg)
{
    __shared__ int s[256];
    int t = threadIdx.x;
    s[t] = (t < 196) ? bsum[t] : 0;
    __syncthreads();
    if (t == 0) {
        int run = 0;
        for (int b = 0; b < 196; b++) { int v = s[b]; s[b] = run; run += v; }
        seg[NN] = NE;
    }
    __syncthreads();
    if (t < 196) boff[t] = s[t];
}

__global__ __launch_bounds__(256) void scan_c_kernel(
    const int* __restrict__ cnt, const int* __restrict__ boff,
    int* __restrict__ seg, int* __restrict__ cur)
{
    __shared__ int s[256];
    int gid = blockIdx.x * 256 + threadIdx.x;
    int v = (gid < NN) ? cnt[gid] : 0;
    s[threadIdx.x] = v;
    __syncthreads();
    for (int off = 1; off < 256; off <<= 1) {
        int t = (threadIdx.x >= off) ? s[threadIdx.x - off] : 0;
        __syncthreads();
        s[threadIdx.x] += t;
        __syncthreads();
    }
    int excl = s[threadIdx.x] - v + boff[blockIdx.x];
    if (gid < NN) { seg[gid] = excl; cur[gid] = excl; }
}

// scatter: one packed 16-B store per edge {src, perm, time_bits, dst}
__global__ __launch_bounds__(256) void scatter_kernel(
    const int* __restrict__ ei, const int* __restrict__ et,
    int* __restrict__ cur, int4* __restrict__ epack)
{
    int gid = blockIdx.x * 256 + threadIdx.x;
    if (gid < NE) {
        int d = ei[NE + gid];
        int pos = atomicAdd(&cur[d], 1);
        int4 p;
        p.x = ei[gid];
        p.y = gid;
        p.z = __float_as_int((float)et[gid]);
        p.w = d;
        epack[pos] = p;
    }
}

// ---------------------------------------------------------------------------
// mega-agg v5: wave per dst node (static grid-stride, wave-uniform n),
// half-wave per edge, DPP row reduction, staged loads.
// No serialized pair-tail: every chunk is the fully-staged 8-edge version
// with per-edge predication (index clamped to s0 -- always valid when the
// loop is entered -- and ex forced to 0 for out-of-range slots).
// ---------------------------------------------------------------------------
__global__ __launch_bounds__(256) void agg_kernel(
    const int4* __restrict__ epack, const float* __restrict__ msg,
    const float* __restrict__ Wt, const float* __restrict__ bt,
    const f16* __restrict__ qh, const f16* __restrict__ kvh,
    const bf16* __restrict__ G, const int* __restrict__ seg,
    float* __restrict__ Sv, float* __restrict__ dnv,
    float* __restrict__ outp)
{
    const int lane = threadIdx.x & 63;
    const int l31 = lane & 31;
    const int hl = (lane >> 4) & 1;   // head of this lane's 16-group
    const int c = lane & 15;
    const int halfid = lane >> 5;

    const float wt0 = Wt[2 * c], wt1 = Wt[2 * c + 1];
    const float bt0 = bt[2 * c], bt1 = bt[2 * c + 1];

    const int gw = blockIdx.x * 4 + (threadIdx.x >> 6);
    const int NW = gridDim.x * 4;

    union QU { uint2 u; f16x2 h[2]; };
    union KVU { uint4 u4; f16x2 h[4]; };

    for (int n = gw; n < NN; n += NW) {
        const int s0 = seg[n], s1 = seg[n + 1];

        QU q; q.u = *(const uint2*)&qh[(size_t)n * DD + 4 * l31];
        const bf16* grow = G + (size_t)n * 192 + 96 * hl;
        const float Gc0 = __bfloat162float(grow[2 * c]);
        const float Gc1 = __bfloat162float(grow[2 * c + 1]);
        const float Gm0 = __bfloat162float(grow[32 + 4 * c]);
        const float Gm1 = __bfloat162float(grow[33 + 4 * c]);
        const float Gm2 = __bfloat162float(grow[34 + 4 * c]);
        const float Gm3 = __bfloat162float(grow[35 + 4 * c]);

        f32x4 av = (f32x4){0.f, 0.f, 0.f, 0.f};
        f32x4 sm = (f32x4){0.f, 0.f, 0.f, 0.f};
        float accd = 0.f, sc0 = 0.f, sc1 = 0.f;

        #pragma unroll 1
        for (int ib = s0; ib < s1; ib += 8) {
            // stage 1: 4 epack loads (predicated by clamping to s0)
            int4 e[4]; bool pr[4];
            #pragma unroll
            for (int u = 0; u < 4; u++) {
                int idx = ib + 2 * u + halfid;
                pr[u] = idx < s1;
                e[u] = epack[pr[u] ? idx : s0];
            }
            // stage 2: 8 gathers (kv + msg), all independent
            KVU kv[4]; float4 m[4];
            #pragma unroll
            for (int u = 0; u < 4; u++) {
                kv[u].u4 = *(const uint4*)&kvh[(size_t)e[u].x * 256 + 8 * l31];
                m[u] = *(const float4*)&msg[((size_t)e[u].y << 6) + 4 * c];
            }
            // stage 3: per-edge partial scores
            float p[4], csa[4], csb[4];
            #pragma unroll
            for (int u = 0; u < 4; u++) {
                float t = __int_as_float(e[u].z);
                csa[u] = __cosf(fmaf(t, wt0, bt0));
                csb[u] = __cosf(fmaf(t, wt1, bt1));
                float pp = fmaf(csa[u], Gc0, csb[u] * Gc1);
                pp = fmaf(m[u].x, Gm0, pp); pp = fmaf(m[u].y, Gm1, pp);
                pp = fmaf(m[u].z, Gm2, pp); pp = fmaf(m[u].w, Gm3, pp);
                pp = FDOT2(q.h[0], kv[u].h[0], pp);
                pp = FDOT2(q.h[1], kv[u].h[1], pp);
                p[u] = pp;
            }
            // stage 4: interleaved DPP row reductions
            #pragma unroll
            for (int u = 0; u < 4; u++) p[u] = rot_add<0x121>(p[u]);
            #pragma unroll
            for (int u = 0; u < 4; u++) p[u] = rot_add<0x122>(p[u]);
            #pragma unroll
            for (int u = 0; u < 4; u++) p[u] = rot_add<0x124>(p[u]);
            #pragma unroll
            for (int u = 0; u < 4; u++) p[u] = rot_add<0x128>(p[u]);
            // stage 5: exp (zeroed for predicated-off lanes) + accumulate
            #pragma unroll
            for (int u = 0; u < 4; u++) {
                float ex = pr[u] ? __expf(p[u] * 0.125f) : 0.f;
                av.x = fmaf(ex, (float)kv[u].h[2][0], av.x);
                av.y = fmaf(ex, (float)kv[u].h[2][1], av.y);
                av.z = fmaf(ex, (float)kv[u].h[3][0], av.z);
                av.w = fmaf(ex, (float)kv[u].h[3][1], av.w);
                accd += ex;
                sc0 = fmaf(ex, csa[u], sc0);
                sc1 = fmaf(ex, csb[u], sc1);
                sm.x = fmaf(ex, m[u].x, sm.x);
                sm.y = fmaf(ex, m[u].y, sm.y);
                sm.z = fmaf(ex, m[u].z, sm.z);
                sm.w = fmaf(ex, m[u].w, sm.w);
            }
        }

        // cross-half combine (halves held alternate edges of the same node)
        av.x += __shfl_xor(av.x, 32);
        av.y += __shfl_xor(av.y, 32);
        av.z += __shfl_xor(av.z, 32);
        av.w += __shfl_xor(av.w, 32);
        accd += __shfl_xor(accd, 32);
        sc0  += __shfl_xor(sc0, 32);
        sc1  += __shfl_xor(sc1, 32);
        sm.x += __shfl_xor(sm.x, 32);
        sm.y += __shfl_xor(sm.y, 32);
        sm.z += __shfl_xor(sm.z, 32);
        sm.w += __shfl_xor(sm.w, 32);

        if (lane < 32) {
            float dn = accd + 1e-16f;
            size_t sb = (size_t)n * 192 + 96 * hl;
            float2 scv; scv.x = sc0; scv.y = sc1;
            *(float2*)&Sv[sb + 2 * c] = scv;
            float4 smv; smv.x = sm.x; smv.y = sm.y; smv.z = sm.z; smv.w = sm.w;
            *(float4*)&Sv[sb + 32 + 4 * c] = smv;
            if (c == 0) dnv[2 * n + hl] = accd;   // lanes 0 and 16

            size_t nb = (size_t)n * HCC + 4 * l31;
            float4 sk = *(const float4*)&outp[nb];   // skip from node_proj
            float4 o;
            o.x = av.x / dn + sk.x;
            o.y = av.y / dn + sk.y;
            o.z = av.z / dn + sk.z;
            o.w = av.w / dn + sk.w;
            *(float4*)&outp[nb] = o;
        }
    }
}

// ---------------------------------------------------------------------------
// K3: epilogue GEMM, out += (S @ We)/dn. 32 nodes/block, S transposed in LDS.
// ---------------------------------------------------------------------------
__global__ __launch_bounds__(256) void epi_kernel(
    const float* __restrict__ Sv, const float* __restrict__ dnv,
    const float* __restrict__ We, float* __restrict__ outp)
{
    __shared__ float st[192 * 36];  // 27.6 KB, st[c*36 + node]
    const int node0 = blockIdx.x * 32;
    for (int idx = threadIdx.x; idx < 32 * 192; idx += 256) {
        int n = idx / 192, c = idx - n * 192;
        int node = node0 + n;
        st[c * 36 + n] = (node < NN) ? Sv[(size_t)node * 192 + c] : 0.f;
    }
    __syncthreads();

    const int wave = threadIdx.x >> 6;
    const int lane = threadIdx.x & 63;
    const int nb = wave * 8;
    const int hoff = (lane < 32) ? 0 : 96;
    const float2* We2 = (const float2*)We;

    float a[8][2];
    #pragma unroll
    for (int n = 0; n < 8; n++) { a[n][0] = 0.f; a[n][1] = 0.f; }

    #pragma unroll 8
    for (int j = 0; j < 96; j++) {
        float2 w = We2[j * 64 + lane];
        const float* sr = &st[(hoff + j) * 36 + nb];
        float sv[8];
        *(float4*)&sv[0] = *(const float4*)sr;
        *(float4*)&sv[4] = *(const float4*)(sr + 4);
        #pragma unroll
        for (int n = 0; n < 8; n++) {
            a[n][0] = fmaf(sv[n], w.x, a[n][0]);
            a[n][1] = fmaf(sv[n], w.y, a[n][1]);
        }
    }

    #pragma unroll 1
    for (int n = 0; n < 8; n++) {
        int node = node0 + nb + n;
        if (node >= NN) break;
        float dn = dnv[node * 2 + (lane >> 5)] + 1e-16f;
        size_t b = (size_t)node * HCC + 2 * lane;
        float2 o = *(const float2*)&outp[b];
        o.x += a[n][0] / dn;
        o.y += a[n][1] / dn;
        *(float2*)&outp[b] = o;
    }
}

extern "C" void kernel_launch(void* const* d_in, const int* in_sizes, int n_in,
                              void* d_out, int out_size, void* d_ws, size_t ws_size,
                              hipStream_t stream) {
    const float* x   = (const float*)d_in[0];
    const int* ei    = (const int*)d_in[1];
    const int* et    = (const int*)d_in[2];
    const float* msg = (const float*)d_in[3];
    const float* Wt  = (const float*)d_in[4];
    const float* bt  = (const float*)d_in[5];
    const float* Wq  = (const float*)d_in[6];
    const float* bq  = (const float*)d_in[7];
    const float* Wk  = (const float*)d_in[8];
    const float* bk  = (const float*)d_in[9];
    const float* Wv  = (const float*)d_in[10];
    const float* bv  = (const float*)d_in[11];
    const float* We  = (const float*)d_in[12];
    const float* Wsk = (const float*)d_in[13];
    const float* bsk = (const float*)d_in[14];

    const size_t nf = (size_t)NN * HCC;
    f16* qh      = (f16*)d_ws;                    // NN*128
    f16* kvh     = qh + nf;                       // NN*256 (k/v interleaved)
    f16* WTh     = kvh + 2 * nf;                  // 512*128
    f16* Weh     = WTh + 512 * 128;               // 96*128
    bf16* G      = (bf16*)(Weh + 96 * 128);       // NN*192
    float* Sv    = (float*)(G + (size_t)NN * 192);// NN*192 f32
    float* dnv   = Sv + (size_t)NN * 192;         // NN*2
    int4* epack  = (int4*)(dnv + (size_t)NN * 2); // NE int4
    int* cnt     = (int*)(epack + NE);
    int* seg     = cnt + NN;                      // NN+1
    int* cur     = seg + NN + 1;
    int* bsum    = cur + NN;
    int* boff    = bsum + 256;
    size_t need  = (size_t)((char*)(boff + 256) - (char*)d_ws);
    if (ws_size < need) return;

    float* outp = (float*)d_out;

    conv_w_kernel<<<(512 * 128 + 96 * 128 + NN + 255) / 256, 256, 0, stream>>>(
        Wq, Wk, Wv, Wsk, We, WTh, Weh, cnt);
    dim3 npgrid((NN + 63) / 64, 4);
    node_proj_kernel<<<npgrid, 256, 0, stream>>>(
        x, WTh, bq, bk, bv, bsk, qh, kvh, outp);
    g_kernel<<<(NN + 63) / 64, 256, 0, stream>>>(qh, Weh, G);
    hist_kernel<<<(NE + 255) / 256, 256, 0, stream>>>(ei, cnt);
    scan_a_kernel<<<196, 256, 0, stream>>>(cnt, bsum);
    scan_b_kernel<<<1, 256, 0, stream>>>(bsum, boff, seg);
    scan_c_kernel<<<196, 256, 0, stream>>>(cnt, boff, seg, cur);
    scatter_kernel<<<(NE + 255) / 256, 256, 0, stream>>>(ei, et, cur, epack);
    agg_kernel<<<2048, 256, 0, stream>>>(
        epack, msg, Wt, bt, qh, kvh, G, seg, Sv, dnv, outp);
    epi_kernel<<<(NN + 31) / 32, 256, 0, stream>>>(Sv, dnv, We, outp);
}